// Round 4
// baseline (97.242 us; speedup 1.0000x reference)
//
#include <hip/hip_runtime.h>

#define NP 16384
#define NS 8192
#define DP 256
#define DS 128
#define DI 128

// ---- ws float offsets ----
#define R_P    0
#define R_S    (R_P + NP)
#define CH_MP  (R_S + NS)          // 256
#define CH_ZP  (CH_MP + 256)      // 256
#define CH_MS  (CH_ZP + 256)      // 128
#define CH_ZS  (CH_MS + 128)      // 128
#define PART_P (CH_ZS + 128)      // 256*DP
#define PART_S (PART_P + 256*DP)  // 128*DS
#define U_P    (PART_S + 128*DS)  // DP
#define U_S    (U_P + DP)         // DS
#define CNT_I  (U_S + DS)         // 1 int slot

// ---- out float offsets ----
#define O1 (NP*DP)
#define O2 (O1 + NP)
#define O3 (O2 + NS*DS)
#define TOTAL (O3 + NS)
#define TOTAL4 (TOTAL/4)

#define GA    512
#define GA_P  384
#define GB    192     // 128 prot blocks + 64 sub blocks, 2 chunks (64 rows) each
#define GB_P  128

__device__ __forceinline__ float wsum64(float s) {
    #pragma unroll
    for (int m = 32; m >= 1; m >>= 1) s += __shfl_xor(s, m, 64);
    return s;
}
__device__ __forceinline__ float wmax64(float s) {
    #pragma unroll
    for (int m = 32; m >= 1; m >>= 1) s = fmaxf(s, __shfl_xor(s, m, 64));
    return s;
}

// ---- kA: per-block weight-colsum preamble (LDS) + row sums; resets ticket ----
__global__ __launch_bounds__(256)
void kA(const float* __restrict__ pn, const float* __restrict__ sn,
        const float* __restrict__ Wpp, const float* __restrict__ bpp,
        const float* __restrict__ Wsp, const float* __restrict__ bsp,
        float* __restrict__ ws) {
    __shared__ float w[DP];
    __shared__ float bsumv;
    const int t = threadIdx.x;
    const int lane = t & 63;
    const int wv = t >> 6;
    if (blockIdx.x == 0 && t == 0) *(int*)(ws + CNT_I) = 0;   // ticket reset
    if (blockIdx.x < GA_P) {
        {
            const float4* row = (const float4*)(Wpp + t * DI);
            float s = 0.f;
            #pragma unroll
            for (int d = 0; d < DI/4; ++d) { float4 v = row[d]; s += v.x + v.y + v.z + v.w; }
            w[t] = s;
        }
        if (t < 64) {
            float b = wsum64(bpp[t] + bpp[64 + t]);
            if (t == 0) bsumv = b;
        }
        __syncthreads();
        const float4 wp = *(const float4*)(w + lane * 4);
        const float bp = bsumv;
        const int nw = GA_P * 4;
        #pragma unroll 2
        for (int row = blockIdx.x * 4 + wv; row < NP; row += nw) {
            const float4 x = *(const float4*)(pn + (size_t)row * DP + lane * 4);
            float s = wsum64(x.x * wp.x + x.y * wp.y + x.z * wp.z + x.w * wp.w);
            if (lane == 0) ws[R_P + row] = s + bp;
        }
    } else {
        if (t < DS) {
            const float4* row = (const float4*)(Wsp + t * DI);
            float s = 0.f;
            #pragma unroll
            for (int d = 0; d < DI/4; ++d) { float4 v = row[d]; s += v.x + v.y + v.z + v.w; }
            w[t] = s;
        }
        if (t < 64) {
            float b = wsum64(bsp[t] + bsp[64 + t]);
            if (t == 0) bsumv = b;
        }
        __syncthreads();
        const float2 wsv = *(const float2*)(w + lane * 2);
        const float bs = bsumv;
        const int nw = (GA - GA_P) * 4;
        #pragma unroll 2
        for (int row = (blockIdx.x - GA_P) * 4 + wv; row < NS; row += nw) {
            const float2 x = *(const float2*)(sn + (size_t)row * DS + lane * 2);
            float s = wsum64(x.x * wsv.x + x.y * wsv.y);
            if (lane == 0) ws[R_S + row] = s + bs;
        }
    }
}

// ---- kB: chunk stats + weighted column partials; LAST block does the combine ----
__global__ __launch_bounds__(1024)
void kB(const float* __restrict__ pn, const float* __restrict__ sn,
        const int* __restrict__ pidx, const int* __restrict__ sidx,
        const float* __restrict__ Wpp, const float* __restrict__ bpp,
        const float* __restrict__ Wsp, const float* __restrict__ bsp,
        const float* __restrict__ Wpo, const float* __restrict__ bpo,
        const float* __restrict__ Wso, const float* __restrict__ bso,
        float* __restrict__ ws) {
    __shared__ float wgt[2][64];
    __shared__ float red[1024];
    __shared__ float red2[1024];
    __shared__ float eP[256], eS[128], mvP[256], mvS[128], vP[128], vS[128];
    __shared__ int lastFlag;
    const int t  = threadIdx.x;
    const int g2 = t >> 9;       // chunk-group within block (0,1)
    const int u  = t & 511;      // index within group
    const int b  = blockIdx.x;

    if (b < GB_P) {
        const int C = b * 2 + g2;                    // prot chunk [0,256)
        if (u < 64) {                                // first wave of group
            const float r = ws[R_P + pidx[C * 64 + u]];
            const float m = wmax64(r);
            const float e = expf(r - m);
            const float z = wsum64(e);
            wgt[g2][u] = e;
            if (u == 0) { ws[CH_MP + C] = m; ws[CH_ZP + C] = z; }
        }
        __syncthreads();
        const int c = u & 255, h = u >> 8;           // col, row-half
        float acc = 0.f;
        const float* basep = pn + ((size_t)C * 64 + h * 32) * DP + c;
        #pragma unroll 8
        for (int k = 0; k < 32; ++k) acc += wgt[g2][h * 32 + k] * basep[(size_t)k * DP];
        red[t] = acc;
        __syncthreads();
        if (u < 256) ws[PART_P + C * DP + u] = red[t] + red[t + 256];
    } else {
        const int C = (b - GB_P) * 2 + g2;           // sub chunk [0,128)
        if (u < 64) {
            const float r = ws[R_S + sidx[C * 64 + u]];
            const float m = wmax64(r);
            const float e = expf(r - m);
            const float z = wsum64(e);
            wgt[g2][u] = e;
            if (u == 0) { ws[CH_MS + C] = m; ws[CH_ZS + C] = z; }
        }
        __syncthreads();
        const int c = u & 127, q4 = u >> 7;          // col, row-quarter
        float acc = 0.f;
        const float* basep = sn + ((size_t)C * 64 + q4 * 16) * DS + c;
        #pragma unroll 8
        for (int k = 0; k < 16; ++k) acc += wgt[g2][q4 * 16 + k] * basep[(size_t)k * DS];
        red[t] = acc;
        __syncthreads();
        if (u < 128) ws[PART_S + C * DS + u] = red[t] + red[t + 128] + red[t + 256] + red[t + 384];
    }

    // ---- ticket: last block performs the combine ----
    __threadfence();
    __syncthreads();
    if (t == 0) lastFlag = (atomicAdd((int*)(ws + CNT_I), 1) == GB - 1);
    __syncthreads();
    if (!lastFlag) return;
    __threadfence();

    // phase 1: global softmax stats -> eP, eS (wave 0 / wave 1)
    if (t < 64) {
        float m0 = ws[CH_MP + t],       m1 = ws[CH_MP + t + 64];
        float m2 = ws[CH_MP + t + 128], m3 = ws[CH_MP + t + 192];
        float M = wmax64(fmaxf(fmaxf(m0, m1), fmaxf(m2, m3)));
        float e0 = expf(m0 - M), e1 = expf(m1 - M), e2 = expf(m2 - M), e3 = expf(m3 - M);
        float z = e0 * ws[CH_ZP + t] + e1 * ws[CH_ZP + t + 64]
                + e2 * ws[CH_ZP + t + 128] + e3 * ws[CH_ZP + t + 192];
        float inv = 1.f / wsum64(z);
        eP[t] = e0 * inv; eP[t + 64] = e1 * inv; eP[t + 128] = e2 * inv; eP[t + 192] = e3 * inv;
    } else if (t < 128) {
        int l = t - 64;
        float m0 = ws[CH_MS + l], m1 = ws[CH_MS + l + 64];
        float M = wmax64(fmaxf(m0, m1));
        float e0 = expf(m0 - M), e1 = expf(m1 - M);
        float z = e0 * ws[CH_ZS + l] + e1 * ws[CH_ZS + l + 64];
        float inv = 1.f / wsum64(z);
        eS[l] = e0 * inv; eS[l + 64] = e1 * inv;
    }
    __syncthreads();
    // phase 2: mvP partials
    {
        const int c = t & 255, q = t >> 8;
        float acc = 0.f;
        #pragma unroll 8
        for (int j = 0; j < 64; ++j) acc += ws[PART_P + (q * 64 + j) * DP + c] * eP[q * 64 + j];
        red[t] = acc;
    }
    __syncthreads();
    // phase 3: mvP fold + mvS partials
    if (t < 256) mvP[t] = red[t] + red[t + 256] + red[t + 512] + red[t + 768];
    {
        const int c = t & 127, q = t >> 7;
        float acc = 0.f;
        #pragma unroll 8
        for (int j = 0; j < 16; ++j) acc += ws[PART_S + (q * 16 + j) * DS + c] * eS[q * 16 + j];
        red2[t] = acc;
    }
    __syncthreads();
    // phase 4: mvS fold + vP partials (vP[d] = bpp[d] + sum_c mvP[c]*Wpp[c][d])
    if (t < 128) {
        float s = 0.f;
        #pragma unroll
        for (int g = 0; g < 8; ++g) s += red2[t + 128 * g];
        mvS[t] = s;
    }
    {
        const int d = t & 127, q = t >> 7;
        float acc = 0.f;
        #pragma unroll 8
        for (int j = 0; j < 32; ++j) acc += mvP[q * 32 + j] * Wpp[(q * 32 + j) * DI + d];
        red[t] = acc;
    }
    __syncthreads();
    // phase 5: vP fold + vS partials (vS[d] = bsp[d] + sum_c mvS[c]*Wsp[c][d])
    if (t < 128) {
        float s = bpp[t];
        #pragma unroll
        for (int g = 0; g < 8; ++g) s += red[t + 128 * g];
        vP[t] = s;
    }
    {
        const int d = t & 127, q = t >> 7;
        float acc = 0.f;
        #pragma unroll 8
        for (int j = 0; j < 16; ++j) acc += mvS[q * 16 + j] * Wsp[(q * 16 + j) * DI + d];
        red2[t] = acc;
    }
    __syncthreads();
    // phase 6: vS fold + uS partials (uS[c] = bso[c] + sum_d vP[d]*Wso[d][c])
    if (t < 128) {
        float s = bsp[t];
        #pragma unroll
        for (int g = 0; g < 8; ++g) s += red2[t + 128 * g];
        vS[t] = s;
    }
    {
        const int c = t & 127, q = t >> 7;
        float acc = 0.f;
        #pragma unroll 8
        for (int j = 0; j < 16; ++j) acc += vP[q * 16 + j] * Wso[(q * 16 + j) * DS + c];
        red[t] = acc;
    }
    __syncthreads();
    // phase 7: uS write + uP partials (uP[c] = bpo[c] + sum_d vS[d]*Wpo[d][c])
    if (t < 128) {
        float s = bso[t];
        #pragma unroll
        for (int g = 0; g < 8; ++g) s += red[t + 128 * g];
        ws[U_S + t] = s;
    }
    {
        const int c = t & 255, q = t >> 8;
        float acc = 0.f;
        #pragma unroll 8
        for (int j = 0; j < 32; ++j) acc += vS[q * 32 + j] * Wpo[(q * 32 + j) * DP + c];
        red2[t] = acc;
    }
    __syncthreads();
    // phase 8: uP write
    if (t < 256) ws[U_P + t] = bpo[t] + red2[t] + red2[t + 256] + red2[t + 512] + red2[t + 768];
}

// ---- kD: finalize all four outputs (float4 grid-stride) ----
__global__ __launch_bounds__(256)
void kD(const float* __restrict__ pn, const float* __restrict__ sn,
        const int* __restrict__ pidx, const int* __restrict__ sidx,
        const float* __restrict__ ws, float* __restrict__ out) {
    __shared__ float up[DP];
    __shared__ float us[DS];
    const int t = threadIdx.x;
    up[t] = ws[U_P + t];
    if (t < DS) us[t] = ws[U_S + t];
    __syncthreads();
    for (int g4 = blockIdx.x * 256 + t; g4 < TOTAL4; g4 += gridDim.x * 256) {
        const int e4 = g4 * 4;
        float4 o;
        if (e4 < O1) {
            float4 x = *(const float4*)(pn + e4);
            int c = e4 & (DP - 1);
            o = make_float4(x.x + up[c], x.y + up[c+1], x.z + up[c+2], x.w + up[c+3]);
        } else if (e4 < O2) {
            int i = e4 - O1;
            int4 v = *(const int4*)(pidx + i);
            o = make_float4((float)v.x, (float)v.y, (float)v.z, (float)v.w);
        } else if (e4 < O3) {
            int i = e4 - O2;
            float4 x = *(const float4*)(sn + i);
            int c = i & (DS - 1);
            o = make_float4(x.x + us[c], x.y + us[c+1], x.z + us[c+2], x.w + us[c+3]);
        } else {
            int i = e4 - O3;
            int4 v = *(const int4*)(sidx + i);
            o = make_float4((float)v.x, (float)v.y, (float)v.z, (float)v.w);
        }
        *(float4*)(out + e4) = o;
    }
}

extern "C" void kernel_launch(void* const* d_in, const int* in_sizes, int n_in,
                              void* d_out, int out_size, void* d_ws, size_t ws_size,
                              hipStream_t stream) {
    const float* pn  = (const float*)d_in[0];
    const float* sn  = (const float*)d_in[1];
    const float* Wpp = (const float*)d_in[2];
    const float* bpp = (const float*)d_in[3];
    const float* Wsp = (const float*)d_in[4];
    const float* bsp = (const float*)d_in[5];
    const float* Wpo = (const float*)d_in[6];
    const float* bpo = (const float*)d_in[7];
    const float* Wso = (const float*)d_in[8];
    const float* bso = (const float*)d_in[9];
    const int* pidx  = (const int*)d_in[10];
    const int* sidx  = (const int*)d_in[11];
    float* ws  = (float*)d_ws;
    float* out = (float*)d_out;

    hipLaunchKernelGGL(kA, dim3(GA), dim3(256), 0, stream, pn, sn, Wpp, bpp, Wsp, bsp, ws);
    hipLaunchKernelGGL(kB, dim3(GB), dim3(1024), 0, stream, pn, sn, pidx, sidx,
                       Wpp, bpp, Wsp, bsp, Wpo, bpo, Wso, bso, ws);
    hipLaunchKernelGGL(kD, dim3(2048), dim3(256), 0, stream, pn, sn, pidx, sidx, ws, out);
}

// Round 5
// 39.906 us; speedup vs baseline: 2.4368x; 2.4368x over previous
//
#include <hip/hip_runtime.h>

#define NP 16384
#define NS 8192
#define DP 256
#define DS 128
#define DI 128

#define NBP 512   // K1 prot blocks
#define NBS 256   // K1 sub blocks

// ---- ws float offsets ----
#define PTP 0                       // [NBP][DP] partial colsums (prot side)
#define PTS (PTP + NBP*DP)          // [NBS][DS]
#define ZPA (PTS + NBS*DS)          // [NBP]
#define ZSA (ZPA + NBP)             // [NBS]
#define U_P (ZSA + NBS)             // DP
#define U_S (U_P + DP)              // DS

// ---- out float offsets ----
#define O1 (NP*DP)
#define O2 (O1 + NP)
#define O3 (O2 + NS*DS)
#define TOTAL (O3 + NS)
#define TOTAL4 (TOTAL/4)

__device__ __forceinline__ float wsum64(float s) {
    #pragma unroll
    for (int m = 32; m >= 1; m >>= 1) s += __shfl_xor(s, m, 64);
    return s;
}

// ---- K1: fused gather-weight + weighted column partial sums ----
// prot block b<NBP: tasks i; weight = exp(dot(pn[pidx[i]], wsum_p)); value pn[i]
// sub  block b>=NBP: tasks j; weight = exp(dot(sn[sidx[j]], wsum_s)); value sn[j]
__global__ __launch_bounds__(256)
void k1(const float* __restrict__ pn, const float* __restrict__ sn,
        const float* __restrict__ Wpp, const float* __restrict__ Wsp,
        const int* __restrict__ pidx, const int* __restrict__ sidx,
        float* __restrict__ ws) {
    __shared__ float wcol[DP];
    __shared__ float racc[4 * DP];
    __shared__ float rz[4];
    const int t = threadIdx.x;
    const int lane = t & 63;
    const int wv = t >> 6;
    const int b = blockIdx.x;

    if (b < NBP) {
        // preamble: wcol[c] = rowsum of Wpp row c (bias constant cancels in softmax)
        {
            const float4* row = (const float4*)(Wpp + t * DI);
            float s = 0.f;
            #pragma unroll
            for (int d = 0; d < DI / 4; ++d) { float4 v = row[d]; s += v.x + v.y + v.z + v.w; }
            wcol[t] = s;
        }
        __syncthreads();
        const float4 wp = *(const float4*)(wcol + lane * 4);
        float4 acc = make_float4(0.f, 0.f, 0.f, 0.f);
        float zacc = 0.f;
        const int base = (b * 4 + wv) * 8;          // 8 tasks per wave
        #pragma unroll
        for (int k = 0; k < 8; k += 2) {
            const int i0 = base + k, i1 = base + k + 1;
            const int g0 = pidx[i0], g1 = pidx[i1];
            const float4 x0 = *(const float4*)(pn + (size_t)g0 * DP + lane * 4);
            const float4 x1 = *(const float4*)(pn + (size_t)g1 * DP + lane * 4);
            float s0 = x0.x * wp.x + x0.y * wp.y + x0.z * wp.z + x0.w * wp.w;
            float s1 = x1.x * wp.x + x1.y * wp.y + x1.z * wp.z + x1.w * wp.w;
            #pragma unroll
            for (int m = 32; m >= 1; m >>= 1) {
                s0 += __shfl_xor(s0, m, 64);
                s1 += __shfl_xor(s1, m, 64);
            }
            const float e0 = __expf(s0), e1 = __expf(s1);
            const float4 y0 = *(const float4*)(pn + (size_t)i0 * DP + lane * 4);
            const float4 y1 = *(const float4*)(pn + (size_t)i1 * DP + lane * 4);
            acc.x += e0 * y0.x + e1 * y1.x;
            acc.y += e0 * y0.y + e1 * y1.y;
            acc.z += e0 * y0.z + e1 * y1.z;
            acc.w += e0 * y0.w + e1 * y1.w;
            zacc += e0 + e1;
        }
        __syncthreads();
        ((float4*)(racc + wv * DP))[lane] = acc;
        if (lane == 0) rz[wv] = zacc;
        __syncthreads();
        if (t < DP) ws[PTP + b * DP + t] = racc[t] + racc[DP + t] + racc[2 * DP + t] + racc[3 * DP + t];
        if (t == 0) ws[ZPA + b] = rz[0] + rz[1] + rz[2] + rz[3];
    } else {
        const int b2 = b - NBP;
        if (t < DS) {
            const float4* row = (const float4*)(Wsp + t * DI);
            float s = 0.f;
            #pragma unroll
            for (int d = 0; d < DI / 4; ++d) { float4 v = row[d]; s += v.x + v.y + v.z + v.w; }
            wcol[t] = s;
        }
        __syncthreads();
        const float2 wp = *(const float2*)(wcol + lane * 2);
        float2 acc = make_float2(0.f, 0.f);
        float zacc = 0.f;
        const int base = (b2 * 4 + wv) * 8;
        #pragma unroll
        for (int k = 0; k < 8; k += 2) {
            const int j0 = base + k, j1 = base + k + 1;
            const int g0 = sidx[j0], g1 = sidx[j1];
            const float2 x0 = *(const float2*)(sn + (size_t)g0 * DS + lane * 2);
            const float2 x1 = *(const float2*)(sn + (size_t)g1 * DS + lane * 2);
            float s0 = x0.x * wp.x + x0.y * wp.y;
            float s1 = x1.x * wp.x + x1.y * wp.y;
            #pragma unroll
            for (int m = 32; m >= 1; m >>= 1) {
                s0 += __shfl_xor(s0, m, 64);
                s1 += __shfl_xor(s1, m, 64);
            }
            const float e0 = __expf(s0), e1 = __expf(s1);
            const float2 y0 = *(const float2*)(sn + (size_t)j0 * DS + lane * 2);
            const float2 y1 = *(const float2*)(sn + (size_t)j1 * DS + lane * 2);
            acc.x += e0 * y0.x + e1 * y1.x;
            acc.y += e0 * y0.y + e1 * y1.y;
            zacc += e0 + e1;
        }
        __syncthreads();
        ((float2*)(racc + wv * DS))[lane] = acc;
        if (lane == 0) rz[wv] = zacc;
        __syncthreads();
        if (t < DS) ws[PTS + b2 * DS + t] = racc[t] + racc[DS + t] + racc[2 * DS + t] + racc[3 * DS + t];
        if (t == 0) ws[ZSA + b2] = rz[0] + rz[1] + rz[2] + rz[3];
    }
}

// ---- K2: reduce partials, normalize, matvec chains (2 blocks x 1024) ----
__global__ __launch_bounds__(1024)
void k2(const float* __restrict__ Wpp, const float* __restrict__ bpp,
        const float* __restrict__ Wsp, const float* __restrict__ bsp,
        const float* __restrict__ Wpo, const float* __restrict__ bpo,
        const float* __restrict__ Wso, const float* __restrict__ bso,
        float* __restrict__ ws) {
    __shared__ float red[1024];
    __shared__ float mv[DP];
    __shared__ float vv[DI];
    const int t = threadIdx.x;
    if (blockIdx.x == 0) {      // P side: mvP -> vP -> u_s
        red[t] = (t < NBP) ? ws[ZPA + t] : 0.f;
        __syncthreads();
        for (int s = 512; s > 0; s >>= 1) { if (t < s) red[t] += red[t + s]; __syncthreads(); }
        const float invZ = 1.f / red[0];
        __syncthreads();
        {
            const int c = t & 255, g = t >> 8;
            float a = 0.f;
            #pragma unroll 8
            for (int b = g; b < NBP; b += 4) a += ws[PTP + b * DP + c];
            red[t] = a;
        }
        __syncthreads();
        if (t < DP) mv[t] = (red[t] + red[t + 256] + red[t + 512] + red[t + 768]) * invZ;
        __syncthreads();
        {
            const int d = t & 127, g = t >> 7;
            float a = 0.f;
            #pragma unroll 8
            for (int c = g * 32; c < g * 32 + 32; ++c) a += mv[c] * Wpp[c * DI + d];
            red[t] = a;
        }
        __syncthreads();
        if (t < DI) {
            float s = bpp[t];
            #pragma unroll
            for (int g = 0; g < 8; ++g) s += red[t + 128 * g];
            vv[t] = s;
        }
        __syncthreads();
        {
            const int c = t & 127, g = t >> 7;
            float a = 0.f;
            #pragma unroll 8
            for (int d = g * 16; d < g * 16 + 16; ++d) a += vv[d] * Wso[d * DS + c];
            red[t] = a;
        }
        __syncthreads();
        if (t < DS) {
            float s = bso[t];
            #pragma unroll
            for (int g = 0; g < 8; ++g) s += red[t + 128 * g];
            ws[U_S + t] = s;
        }
    } else {                    // S side: mvS -> vS -> u_p
        red[t] = (t < NBS) ? ws[ZSA + t] : 0.f;
        __syncthreads();
        for (int s = 512; s > 0; s >>= 1) { if (t < s) red[t] += red[t + s]; __syncthreads(); }
        const float invZ = 1.f / red[0];
        __syncthreads();
        {
            const int c = t & 127, g = t >> 7;
            float a = 0.f;
            #pragma unroll 8
            for (int b = g; b < NBS; b += 8) a += ws[PTS + b * DS + c];
            red[t] = a;
        }
        __syncthreads();
        if (t < DS) {
            float a = 0.f;
            #pragma unroll
            for (int g = 0; g < 8; ++g) a += red[t + 128 * g];
            mv[t] = a * invZ;
        }
        __syncthreads();
        {
            const int d = t & 127, g = t >> 7;
            float a = 0.f;
            #pragma unroll 8
            for (int c = g * 16; c < g * 16 + 16; ++c) a += mv[c] * Wsp[c * DI + d];
            red[t] = a;
        }
        __syncthreads();
        if (t < DI) {
            float s = bsp[t];
            #pragma unroll
            for (int g = 0; g < 8; ++g) s += red[t + 128 * g];
            vv[t] = s;
        }
        __syncthreads();
        {
            const int c = t & 255, g = t >> 8;
            float a = 0.f;
            #pragma unroll 8
            for (int d = g * 32; d < g * 32 + 32; ++d) a += vv[d] * Wpo[d * DP + c];
            red[t] = a;
        }
        __syncthreads();
        if (t < DP) {
            ws[U_P + t] = bpo[t] + red[t] + red[t + 256] + red[t + 512] + red[t + 768];
        }
    }
}

// ---- K3: finalize all four outputs (float4 grid-stride) ----
__global__ __launch_bounds__(256)
void k3(const float* __restrict__ pn, const float* __restrict__ sn,
        const int* __restrict__ pidx, const int* __restrict__ sidx,
        const float* __restrict__ ws, float* __restrict__ out) {
    __shared__ float up[DP];
    __shared__ float us[DS];
    const int t = threadIdx.x;
    up[t] = ws[U_P + t];
    if (t < DS) us[t] = ws[U_S + t];
    __syncthreads();
    for (int g4 = blockIdx.x * 256 + t; g4 < TOTAL4; g4 += gridDim.x * 256) {
        const int e4 = g4 * 4;
        float4 o;
        if (e4 < O1) {
            float4 x = *(const float4*)(pn + e4);
            int c = e4 & (DP - 1);
            o = make_float4(x.x + up[c], x.y + up[c+1], x.z + up[c+2], x.w + up[c+3]);
        } else if (e4 < O2) {
            int i = e4 - O1;
            int4 v = *(const int4*)(pidx + i);
            o = make_float4((float)v.x, (float)v.y, (float)v.z, (float)v.w);
        } else if (e4 < O3) {
            int i = e4 - O2;
            float4 x = *(const float4*)(sn + i);
            int c = i & (DS - 1);
            o = make_float4(x.x + us[c], x.y + us[c+1], x.z + us[c+2], x.w + us[c+3]);
        } else {
            int i = e4 - O3;
            int4 v = *(const int4*)(sidx + i);
            o = make_float4((float)v.x, (float)v.y, (float)v.z, (float)v.w);
        }
        *(float4*)(out + e4) = o;
    }
}

extern "C" void kernel_launch(void* const* d_in, const int* in_sizes, int n_in,
                              void* d_out, int out_size, void* d_ws, size_t ws_size,
                              hipStream_t stream) {
    const float* pn  = (const float*)d_in[0];
    const float* sn  = (const float*)d_in[1];
    const float* Wpp = (const float*)d_in[2];
    const float* bpp = (const float*)d_in[3];
    const float* Wsp = (const float*)d_in[4];
    const float* bsp = (const float*)d_in[5];
    const float* Wpo = (const float*)d_in[6];
    const float* bpo = (const float*)d_in[7];
    const float* Wso = (const float*)d_in[8];
    const float* bso = (const float*)d_in[9];
    const int* pidx  = (const int*)d_in[10];
    const int* sidx  = (const int*)d_in[11];
    float* ws  = (float*)d_ws;
    float* out = (float*)d_out;

    hipLaunchKernelGGL(k1, dim3(NBP + NBS), dim3(256), 0, stream,
                       pn, sn, Wpp, Wsp, pidx, sidx, ws);
    hipLaunchKernelGGL(k2, dim3(2), dim3(1024), 0, stream,
                       Wpp, bpp, Wsp, bsp, Wpo, bpo, Wso, bso, ws);
    hipLaunchKernelGGL(k3, dim3(2048), dim3(256), 0, stream,
                       pn, sn, pidx, sidx, ws, out);
}

// Round 6
// 30.694 us; speedup vs baseline: 3.1681x; 1.3001x over previous
//
#include <hip/hip_runtime.h>

#define NP 16384
#define NS 8192
#define DP 256
#define DS 128
#define DI 128

#define NBP 128   // k1 prot blocks (128 rows each)
#define NBS 64    // k1 sub blocks (128 rows each)

// ---- ws float offsets ----
#define RP_OFF 0                     // [NBP][DS]  projected prot partials (-> u_s)
#define RS_OFF (RP_OFF + NBP*DS)     // [NBS][DP]  projected sub partials (-> u_p)
#define ZP_OFF (RS_OFF + NBS*DP)     // [NBP]
#define ZS_OFF (ZP_OFF + NBP)        // [NBS]
#define BSC    (ZS_OFF + NBS)        // [DS]  bso + Wso^T bpp
#define BPC    (BSC + DS)            // [DP]  bpo + Wpo^T bsp

// ---- out float4 offsets ----
#define O1 (NP*DP)
#define O2 (O1 + NP)
#define O3 (O2 + NS*DS)
#define TOTAL (O3 + NS)
#define TOTAL4 (TOTAL/4)
#define GK2 1024
#define CHUNK (TOTAL4/GK2)   // 1286 exactly

__device__ __forceinline__ float wsum64(float s) {
    #pragma unroll
    for (int m = 32; m >= 1; m >>= 1) s += __shfl_xor(s, m, 64);
    return s;
}

// ---- k1: fused gather-weight + weighted colsum + per-block projection ----
__global__ __launch_bounds__(512)
void k1(const float* __restrict__ pn, const float* __restrict__ sn,
        const float* __restrict__ Wpp, const float* __restrict__ bpp,
        const float* __restrict__ Wsp, const float* __restrict__ bsp,
        const float* __restrict__ Wpo, const float* __restrict__ bpo,
        const float* __restrict__ Wso, const float* __restrict__ bso,
        const int* __restrict__ pidx, const int* __restrict__ sidx,
        float* __restrict__ ws) {
    __shared__ float wcol[DP];
    __shared__ float racc[8 * DP];
    __shared__ float rz[8];
    __shared__ float acc2[DP];
    __shared__ float qv[DI];
    __shared__ float red[512];
    const int t = threadIdx.x;
    const int lane = t & 63;
    const int wv = t >> 6;
    const int b = blockIdx.x;

    if (b < NBP) {
        // ---- prot side: weights exp(dot(pn[pidx[i]], wsum_p)), values pn[i] ----
        if (t < DP) {
            const float4* row = (const float4*)(Wpp + t * DI);
            float s = 0.f;
            #pragma unroll
            for (int d = 0; d < DI / 4; ++d) { float4 v = row[d]; s += v.x + v.y + v.z + v.w; }
            wcol[t] = s;
        }
        __syncthreads();
        const float4 wp = *(const float4*)(wcol + lane * 4);
        float4 acc = make_float4(0.f, 0.f, 0.f, 0.f);
        float z = 0.f;
        const int base = (b * 8 + wv) * 16;
        #pragma unroll
        for (int k = 0; k < 16; k += 2) {
            const int i0 = base + k, i1 = base + k + 1;
            const int g0 = pidx[i0], g1 = pidx[i1];
            const float4 x0 = *(const float4*)(pn + (size_t)g0 * DP + lane * 4);
            const float4 x1 = *(const float4*)(pn + (size_t)g1 * DP + lane * 4);
            float s0 = x0.x * wp.x + x0.y * wp.y + x0.z * wp.z + x0.w * wp.w;
            float s1 = x1.x * wp.x + x1.y * wp.y + x1.z * wp.z + x1.w * wp.w;
            #pragma unroll
            for (int m = 32; m >= 1; m >>= 1) {
                s0 += __shfl_xor(s0, m, 64);
                s1 += __shfl_xor(s1, m, 64);
            }
            const float e0 = __expf(s0), e1 = __expf(s1);
            const float4 y0 = *(const float4*)(pn + (size_t)i0 * DP + lane * 4);
            const float4 y1 = *(const float4*)(pn + (size_t)i1 * DP + lane * 4);
            acc.x += e0 * y0.x + e1 * y1.x;
            acc.y += e0 * y0.y + e1 * y1.y;
            acc.z += e0 * y0.z + e1 * y1.z;
            acc.w += e0 * y0.w + e1 * y1.w;
            z += e0 + e1;
        }
        ((float4*)(racc + wv * DP))[lane] = acc;
        if (lane == 0) rz[wv] = z;
        __syncthreads();
        if (t < DP) {
            float s = 0.f;
            #pragma unroll
            for (int w = 0; w < 8; ++w) s += racc[w * DP + t];
            acc2[t] = s;
        }
        if (t == 0) {
            float s = 0.f;
            #pragma unroll
            for (int w = 0; w < 8; ++w) s += rz[w];
            ws[ZP_OFF + b] = s;
        }
        __syncthreads();
        // stage A: q[d] = sum_c acc2[c]*Wpp[c][d]
        {
            const int d = t & 127, g = t >> 7;
            float a = 0.f;
            #pragma unroll 8
            for (int c = g * 64; c < g * 64 + 64; ++c) a += acc2[c] * Wpp[c * DI + d];
            red[t] = a;
        }
        __syncthreads();
        if (t < DI) qv[t] = red[t] + red[t + 128] + red[t + 256] + red[t + 384];
        __syncthreads();
        // stage B: r[c] = sum_d qv[d]*Wso[d][c]
        {
            const int c = t & 127, g = t >> 7;
            float a = 0.f;
            #pragma unroll 8
            for (int d = g * 32; d < g * 32 + 32; ++d) a += qv[d] * Wso[d * DS + c];
            red[t] = a;
        }
        __syncthreads();
        if (t < DS) ws[RP_OFF + b * DS + t] = red[t] + red[t + 128] + red[t + 256] + red[t + 384];
        if (b == 0) {   // BS_const = bso + Wso^T bpp
            __syncthreads();
            {
                const int c = t & 127, g = t >> 7;
                float a = 0.f;
                #pragma unroll 8
                for (int d = g * 32; d < g * 32 + 32; ++d) a += bpp[d] * Wso[d * DS + c];
                red[t] = a;
            }
            __syncthreads();
            if (t < DS) ws[BSC + t] = bso[t] + red[t] + red[t + 128] + red[t + 256] + red[t + 384];
        }
    } else {
        // ---- sub side ----
        const int b2 = b - NBP;
        if (t < DS) {
            const float4* row = (const float4*)(Wsp + t * DI);
            float s = 0.f;
            #pragma unroll
            for (int d = 0; d < DI / 4; ++d) { float4 v = row[d]; s += v.x + v.y + v.z + v.w; }
            wcol[t] = s;
        }
        __syncthreads();
        const float2 wp = *(const float2*)(wcol + lane * 2);
        float2 acc = make_float2(0.f, 0.f);
        float z = 0.f;
        const int base = (b2 * 8 + wv) * 16;
        #pragma unroll
        for (int k = 0; k < 16; k += 2) {
            const int j0 = base + k, j1 = base + k + 1;
            const int g0 = sidx[j0], g1 = sidx[j1];
            const float2 x0 = *(const float2*)(sn + (size_t)g0 * DS + lane * 2);
            const float2 x1 = *(const float2*)(sn + (size_t)g1 * DS + lane * 2);
            float s0 = x0.x * wp.x + x0.y * wp.y;
            float s1 = x1.x * wp.x + x1.y * wp.y;
            #pragma unroll
            for (int m = 32; m >= 1; m >>= 1) {
                s0 += __shfl_xor(s0, m, 64);
                s1 += __shfl_xor(s1, m, 64);
            }
            const float e0 = __expf(s0), e1 = __expf(s1);
            const float2 y0 = *(const float2*)(sn + (size_t)j0 * DS + lane * 2);
            const float2 y1 = *(const float2*)(sn + (size_t)j1 * DS + lane * 2);
            acc.x += e0 * y0.x + e1 * y1.x;
            acc.y += e0 * y0.y + e1 * y1.y;
            z += e0 + e1;
        }
        ((float2*)(racc + wv * DS))[lane] = acc;
        if (lane == 0) rz[wv] = z;
        __syncthreads();
        if (t < DS) {
            float s = 0.f;
            #pragma unroll
            for (int w = 0; w < 8; ++w) s += racc[w * DS + t];
            acc2[t] = s;
        }
        if (t == 0) {
            float s = 0.f;
            #pragma unroll
            for (int w = 0; w < 8; ++w) s += rz[w];
            ws[ZS_OFF + b2] = s;
        }
        __syncthreads();
        // stage A: q[d] = sum_c acc2[c]*Wsp[c][d]
        {
            const int d = t & 127, g = t >> 7;
            float a = 0.f;
            #pragma unroll 8
            for (int c = g * 32; c < g * 32 + 32; ++c) a += acc2[c] * Wsp[c * DI + d];
            red[t] = a;
        }
        __syncthreads();
        if (t < DI) qv[t] = red[t] + red[t + 128] + red[t + 256] + red[t + 384];
        __syncthreads();
        // stage B: r[c] = sum_d qv[d]*Wpo[d][c], c < 256
        {
            const int c = t & 255, g = t >> 8;
            float a = 0.f;
            #pragma unroll 8
            for (int d = g * 64; d < g * 64 + 64; ++d) a += qv[d] * Wpo[d * DP + c];
            red[t] = a;
        }
        __syncthreads();
        if (t < DP) ws[RS_OFF + b2 * DP + t] = red[t] + red[t + 256];
        if (b2 == 0) {  // BP_const = bpo + Wpo^T bsp
            __syncthreads();
            {
                const int c = t & 255, g = t >> 8;
                float a = 0.f;
                #pragma unroll 8
                for (int d = g * 64; d < g * 64 + 64; ++d) a += bsp[d] * Wpo[d * DP + c];
                red[t] = a;
            }
            __syncthreads();
            if (t < DP) ws[BPC + t] = bpo[t] + red[t] + red[t + 256];
        }
    }
}

// ---- k2: per-block redundant combine (only the side needed) + finalize ----
__global__ __launch_bounds__(512)
void k2(const float* __restrict__ pn, const float* __restrict__ sn,
        const int* __restrict__ pidx, const int* __restrict__ sidx,
        const float* __restrict__ ws, float* __restrict__ out) {
    __shared__ float up[DP];
    __shared__ float us[DS];
    __shared__ float red[512];
    __shared__ float zsh[2];
    const int t = threadIdx.x;
    const int lane = t & 63;
    const int wv = t >> 6;
    const int b = blockIdx.x;
    const int start4 = b * CHUNK;
    const int end4 = start4 + CHUNK;

    if (wv == 0) {
        float z = ws[ZP_OFF + lane] + ws[ZP_OFF + 64 + lane];
        z = wsum64(z);
        if (lane == 0) zsh[0] = z;
    } else if (wv == 1) {
        float z = ws[ZS_OFF + lane];
        z = wsum64(z);
        if (lane == 0) zsh[1] = z;
    }
    __syncthreads();
    const float invZp = 1.f / zsh[0];
    const float invZs = 1.f / zsh[1];

    const bool needP = start4 < (O1 / 4);
    const bool needS = (end4 > (O2 / 4)) && (start4 < (O3 / 4));

    if (needP) {   // u_p from sub-side projected partials
        {
            const int c = t & 255, g = t >> 8;
            float a = 0.f;
            #pragma unroll 8
            for (int b2 = g * 32; b2 < g * 32 + 32; ++b2) a += ws[RS_OFF + b2 * DP + c];
            red[t] = a;
        }
        __syncthreads();
        if (t < DP) up[t] = ws[BPC + t] + invZs * (red[t] + red[t + 256]);
        __syncthreads();
    }
    if (needS) {   // u_s from prot-side projected partials
        {
            const int c = t & 127, g = t >> 7;
            float a = 0.f;
            #pragma unroll 8
            for (int b1 = g * 32; b1 < g * 32 + 32; ++b1) a += ws[RP_OFF + b1 * DS + c];
            red[t] = a;
        }
        __syncthreads();
        if (t < DS) us[t] = ws[BSC + t] + invZp * (red[t] + red[t + 128] + red[t + 256] + red[t + 384]);
        __syncthreads();
    }

    for (int g4 = start4 + t; g4 < end4; g4 += 512) {
        const int e4 = g4 * 4;
        float4 o;
        if (e4 < O1) {
            float4 x = *(const float4*)(pn + e4);
            int c = e4 & (DP - 1);
            o = make_float4(x.x + up[c], x.y + up[c + 1], x.z + up[c + 2], x.w + up[c + 3]);
        } else if (e4 < O2) {
            int i = e4 - O1;
            int4 v = *(const int4*)(pidx + i);
            o = make_float4((float)v.x, (float)v.y, (float)v.z, (float)v.w);
        } else if (e4 < O3) {
            int i = e4 - O2;
            float4 x = *(const float4*)(sn + i);
            int c = i & (DS - 1);
            o = make_float4(x.x + us[c], x.y + us[c + 1], x.z + us[c + 2], x.w + us[c + 3]);
        } else {
            int i = e4 - O3;
            int4 v = *(const int4*)(sidx + i);
            o = make_float4((float)v.x, (float)v.y, (float)v.z, (float)v.w);
        }
        *(float4*)(out + e4) = o;
    }
}

extern "C" void kernel_launch(void* const* d_in, const int* in_sizes, int n_in,
                              void* d_out, int out_size, void* d_ws, size_t ws_size,
                              hipStream_t stream) {
    const float* pn  = (const float*)d_in[0];
    const float* sn  = (const float*)d_in[1];
    const float* Wpp = (const float*)d_in[2];
    const float* bpp = (const float*)d_in[3];
    const float* Wsp = (const float*)d_in[4];
    const float* bsp = (const float*)d_in[5];
    const float* Wpo = (const float*)d_in[6];
    const float* bpo = (const float*)d_in[7];
    const float* Wso = (const float*)d_in[8];
    const float* bso = (const float*)d_in[9];
    const int* pidx  = (const int*)d_in[10];
    const int* sidx  = (const int*)d_in[11];
    float* ws  = (float*)d_ws;
    float* out = (float*)d_out;

    hipLaunchKernelGGL(k1, dim3(NBP + NBS), dim3(512), 0, stream,
                       pn, sn, Wpp, bpp, Wsp, bsp, Wpo, bpo, Wso, bso, pidx, sidx, ws);
    hipLaunchKernelGGL(k2, dim3(GK2), dim3(512), 0, stream,
                       pn, sn, pidx, sidx, ws, out);
}